// Round 8
// baseline (33.789 us; speedup 1.0000x reference)
//
#include <hip/hip_runtime.h>

#define SENT (-3.402823466e38f)

// ws layout (floats)
#define OFF_WQT   0            // [256k][256c]
#define OFF_WVNT  65536        // [256k][256c] (Wv node cols)
#define OFF_WPT   131072       // [256k][256o]
#define OFF_WVET  196608       // [64e][256c]
#define OFF_QKP   212992       // [512r][512he]
#define OFF_VNODE 475136       // [512r][256c]

__device__ __forceinline__ float dot4(float4 a, float4 b) {
    return a.x*b.x + a.y*b.y + a.z*b.z + a.w*b.w;
}

// ---------------- K0: weight transposes (WqT, WvnT, WpT, WvEt) ------------
__global__ void k0_setup(const float* __restrict__ Wq, const float* __restrict__ Wv,
                         const float* __restrict__ Wp,
                         float* __restrict__ WqT, float* __restrict__ WvnT,
                         float* __restrict__ WpT, float* __restrict__ WvEt) {
    __shared__ float tile[32][33];
    int blk = blockIdx.x, tid = threadIdx.x;
    if (blk < 192) {
        int m = blk >> 6, t = blk & 63;
        int tr = t >> 3, tc = t & 7;
        const float* src; int ss; float* dst;
        if (m == 0)      { src = Wq; ss = 256; dst = WqT; }
        else if (m == 1) { src = Wv; ss = 320; dst = WvnT; }
        else             { src = Wp; ss = 256; dst = WpT; }
        #pragma unroll
        for (int i = 0; i < 4; ++i) {
            int rr = i*8 + (tid >> 5), kk = tid & 31;
            tile[rr][kk] = src[(size_t)(tr*32 + rr)*ss + tc*32 + kk];
        }
        __syncthreads();
        #pragma unroll
        for (int i = 0; i < 4; ++i) {
            int kk = i*8 + (tid >> 5), rr = tid & 31;
            dst[(size_t)(tc*32 + kk)*256 + tr*32 + rr] = tile[rr][kk];
        }
    } else {                  // WvEt: [256c][64e] -> [64e][256c], 16 tiles
        int t = blk - 192;
        int tr = t >> 1, tc = t & 1;
        #pragma unroll
        for (int i = 0; i < 4; ++i) {
            int rr = i*8 + (tid >> 5), kk = tid & 31;
            tile[rr][kk] = Wv[(size_t)(tr*32 + rr)*320 + 256 + tc*32 + kk];
        }
        __syncthreads();
        #pragma unroll
        for (int i = 0; i < 4; ++i) {
            int kk = i*8 + (tid >> 5), rr = tid & 31;
            WvEt[(size_t)(tc*32 + kk)*256 + tr*32 + rr] = tile[rr][kk];
        }
    }
}

// ---------------- K1: batched q -> qkp, vnode ------------------------------
// grid 512: rb = blk>>2 (4 rows), cb = blk&3 (64 cols = heads {2cb,2cb+1}).
__global__ __launch_bounds__(512, 4)
void k1_proj(const float* __restrict__ x, const float* __restrict__ WqT,
             const float* __restrict__ WvnT, const float* __restrict__ Wk,
             const float* __restrict__ bq, const float* __restrict__ bv,
             float* __restrict__ vnode, float* __restrict__ qkp) {
    __shared__ float xL[4][256];
    __shared__ float redq[8][256];   // [kq][r*64+cc]
    __shared__ float redv[8][256];
    __shared__ float qls[4][64];
    int tid = threadIdx.x;
    int wv = tid >> 6, lane = tid & 63;
    int rb = blockIdx.x >> 2, cb = blockIdx.x & 3;
    int r0 = rb*4, c0 = cb*64, h0 = cb*2;

    {   // stage x rows (coalesced float2)
        int idx = tid*2, r = idx >> 8, k = idx & 255;
        float2 v = *(const float2*)&x[(size_t)(r0 + r)*256 + k];
        xL[r][k] = v.x; xL[r][k+1] = v.y;
    }
    __syncthreads();

    {   // P1: wave = kq (32 k's), lane = cc. Coalesced 256B weight streams.
        int c = c0 + lane;
        const float* wq = WqT + (size_t)(wv*32)*256 + c;
        const float* wn = WvnT + (size_t)(wv*32)*256 + c;
        float aq[4] = {0,0,0,0}, av[4] = {0,0,0,0};
        #pragma unroll 8
        for (int k = 0; k < 32; ++k) {
            float q4 = wq[(size_t)k*256];
            float n4 = wn[(size_t)k*256];
            #pragma unroll
            for (int r = 0; r < 4; ++r) {
                float xv = xL[r][wv*32 + k];   // wave-uniform broadcast
                aq[r] += xv * q4;
                av[r] += xv * n4;
            }
        }
        #pragma unroll
        for (int r = 0; r < 4; ++r) {
            redq[wv][r*64 + lane] = aq[r];
            redv[wv][r*64 + lane] = av[r];
        }
    }
    __syncthreads();

    {   // reduce: tid = (mat, r, cc): 2*4*64 = 512
        int mat = tid >> 8, rr = (tid >> 6) & 3, cc = lane;
        const float (*red)[256] = mat ? redv : redq;
        float s = 0.f;
        #pragma unroll
        for (int kq = 0; kq < 8; ++kq) s += red[kq][rr*64 + cc];
        if (mat == 0) qls[rr][cc] = s + bq[c0 + cc];
        else vnode[(size_t)(r0 + rr)*256 + c0 + cc] = s + bv[c0 + cc];
    }
    __syncthreads();

    {   // P2: qkp[r][h][e]; thread = (rr, hl, e). Raw Wk edge cols, 256B coalesced.
        int rr = tid >> 7, hl = (tid >> 6) & 1, e = lane;
        const float* wk = Wk + (size_t)((h0 + hl)*32)*320 + 256 + e;
        float a = 0.f;
        #pragma unroll 8
        for (int d = 0; d < 32; ++d)
            a += qls[rr][hl*32 + d] * wk[(size_t)d*320];
        qkp[(size_t)(r0 + rr)*512 + (h0 + hl)*64 + e] = a * 0.17677669529663687f;
    }
}

// ---------------- KB: attention + y + out, 2 rows/block --------------------
// grid 256, 1024 thr (16 waves). Wave = (row, head) for attention.
__global__ __launch_bounds__(1024, 1)
void kB(const float* __restrict__ edge, const int* __restrict__ msk,
        const float* __restrict__ qkp, const float* __restrict__ vnode,
        const float* __restrict__ WvEt, const float* __restrict__ WpT,
        const float* __restrict__ bp, float* __restrict__ out) {
    __shared__ float eds[2][128*68];    // 69632 B, stride 68
    __shared__ float qkpL[2][512];
    __shared__ float mval[2][128];
    __shared__ float aggF[2][512];      // [r][h*64+e]
    __shared__ float yL[2][256];
    __shared__ float redY[2][2][256];   // [eh][r][c]
    __shared__ float redP[8][512];      // [kq][r*256+o]

    int tid = threadIdx.x;
    int wv = tid >> 6, lane = tid & 63;
    int rA = blockIdx.x * 2;

    {   // edge loads for both rows (coalesced float4)
        const float* eg = edge + (size_t)rA * 8192;
        float4 ef[4];
        #pragma unroll
        for (int it = 0; it < 4; ++it)
            ef[it] = *(const float4*)(eg + (size_t)(tid + 1024*it)*4);
        #pragma unroll
        for (int it = 0; it < 4; ++it) {
            int fid = (tid + 1024*it)*4;
            int r = fid >> 13, fr = fid & 8191, j = fr >> 6, e = fr & 63;
            *(float4*)&eds[r][j*68 + e] = ef[it];
        }
    }
    qkpL[tid >> 9][tid & 511] = qkp[(size_t)(rA + (tid >> 9))*512 + (tid & 511)];
    if (tid < 256) {
        int r = tid >> 7, j = tid & 127;
        mval[r][j] = (msk[(size_t)(rA + r)*128 + j] != 0) ? 1.0f : 0.0f;
    }
    __syncthreads();

    {   // attention: wave = (r, h)
        int r = wv >> 3, h = wv & 7;
        float lg0, lg1;
        {
            float a0 = 0.f, a1 = 0.f;
            #pragma unroll
            for (int ec = 0; ec < 16; ++ec) {
                float4 qa = *(float4*)&qkpL[r][h*64 + ec*4];          // uniform
                float4 e0v = *(float4*)&eds[r][lane*68 + ec*4];
                float4 e1v = *(float4*)&eds[r][(64 + lane)*68 + ec*4];
                a0 += dot4(e0v, qa); a1 += dot4(e1v, qa);
            }
            lg0 = (mval[r][lane] > 0.5f) ? a0 : SENT;
            lg1 = (mval[r][64 + lane] > 0.5f) ? a1 : SENT;
        }
        float m = fmaxf(lg0, lg1);
        #pragma unroll
        for (int off = 32; off >= 1; off >>= 1) m = fmaxf(m, __shfl_xor(m, off));
        float e0 = __expf(lg0 - m), e1 = __expf(lg1 - m);
        float s = e0 + e1;
        #pragma unroll
        for (int off = 32; off >= 1; off >>= 1) s += __shfl_xor(s, off);
        float inv = 1.0f / s;
        float att0 = e0 * inv, att1 = e1 * inv;

        int jj = lane >> 4, ec = lane & 15;
        float4 acc = {0,0,0,0};
        #pragma unroll
        for (int js = 0; js < 16; ++js) {
            int j = js*4 + jj;
            float w = __shfl(att0, j);
            float4 ev = *(float4*)&eds[r][j*68 + ec*4];
            acc.x += w*ev.x; acc.y += w*ev.y; acc.z += w*ev.z; acc.w += w*ev.w;
        }
        #pragma unroll
        for (int js = 0; js < 16; ++js) {
            int j = js*4 + jj;
            float w = __shfl(att1, j);
            float4 ev = *(float4*)&eds[r][(64 + j)*68 + ec*4];
            acc.x += w*ev.x; acc.y += w*ev.y; acc.z += w*ev.z; acc.w += w*ev.w;
        }
        #pragma unroll
        for (int off = 16; off <= 32; off <<= 1) {
            acc.x += __shfl_xor(acc.x, off); acc.y += __shfl_xor(acc.y, off);
            acc.z += __shfl_xor(acc.z, off); acc.w += __shfl_xor(acc.w, off);
        }
        if (jj == 0) *(float4*)&aggF[r][h*64 + ec*4] = acc;
    }
    __syncthreads();

    {   // phase A: y[r][c] = vnode + sum_e aggF[r][h(c)][e]*WvEt[e][c]
        int eh = tid >> 9, r = (tid >> 8) & 1, c = tid & 255;
        int hb = (c >> 5)*64;
        const float* wv_ = WvEt + (size_t)(eh*32)*256 + c;
        float a = (eh == 0) ? vnode[(size_t)(rA + r)*256 + c] : 0.f;
        #pragma unroll 8
        for (int e = 0; e < 32; ++e)
            a += aggF[r][hb + eh*32 + e] * wv_[(size_t)e*256];
        redY[eh][r][c] = a;
    }
    __syncthreads();
    if (tid < 512) {
        int r = tid >> 8, c = tid & 255;
        yL[r][c] = redY[0][r][c] + redY[1][r][c];
    }
    __syncthreads();

    {   // phase B: out-proj partials. wave = (kq, r); lane = o within chunk.
        int kq = wv >> 1, r = wv & 1;
        #pragma unroll
        for (int cp = 0; cp < 4; ++cp) {
            int o = cp*64 + lane;
            const float* wp = WpT + (size_t)(kq*32)*256 + o;
            float a = 0.f;
            #pragma unroll 8
            for (int k = 0; k < 32; ++k)
                a += yL[r][kq*32 + k] * wp[(size_t)k*256];  // yL wave-uniform
            redP[kq][r*256 + o] = a;
        }
    }
    __syncthreads();

    if (tid < 512) {
        int r = tid >> 8, o = tid & 255;
        float s = bp[o];
        #pragma unroll
        for (int kq = 0; kq < 8; ++kq) s += redP[kq][r*256 + o];
        out[(size_t)(rA + r)*256 + o] = s;
    }
}

extern "C" void kernel_launch(void* const* d_in, const int* in_sizes, int n_in,
                              void* d_out, int out_size, void* d_ws, size_t ws_size,
                              hipStream_t stream) {
    (void)in_sizes; (void)n_in; (void)out_size; (void)ws_size;
    const float* x    = (const float*)d_in[0];
    // d_in[1] aux_x: unused by reference
    const int*   msk  = (const int*)d_in[2];
    const float* edge = (const float*)d_in[3];
    const float* Wq   = (const float*)d_in[4];
    const float* bq   = (const float*)d_in[5];
    const float* Wk   = (const float*)d_in[6];
    // d_in[7] bk: constant over j -> cancels in softmax
    const float* Wv   = (const float*)d_in[8];
    const float* bv   = (const float*)d_in[9];
    const float* Wp   = (const float*)d_in[10];
    const float* bp   = (const float*)d_in[11];
    float* out = (float*)d_out;
    float* ws  = (float*)d_ws;

    float* WqT   = ws + OFF_WQT;
    float* WvnT  = ws + OFF_WVNT;
    float* WpT   = ws + OFF_WPT;
    float* WvEt  = ws + OFF_WVET;
    float* qkp   = ws + OFF_QKP;
    float* vnode = ws + OFF_VNODE;

    k0_setup<<<208, 256, 0, stream>>>(Wq, Wv, Wp, WqT, WvnT, WpT, WvEt);
    k1_proj<<<512, 512, 0, stream>>>(x, WqT, WvnT, Wk, bq, bv, vnode, qkp);
    kB<<<256, 1024, 0, stream>>>(edge, msk, qkp, vnode, WvEt, WpT, bp, out);
}

// Round 9
// 21.494 us; speedup vs baseline: 1.5720x; 1.5720x over previous
//
#include <hip/hip_runtime.h>

#define SENT (-3.402823466e38f)

typedef __attribute__((ext_vector_type(8))) short short8;
typedef __attribute__((ext_vector_type(4))) float floatx4;

// ws float offsets
#define OFF_QKP   0         // ushort[512][512]  (qkp, bf16, scale baked in)
#define OFF_AGG   131072    // ushort[512][512]  (agg, bf16)
#define OFF_VNODE 262144    // float [512][256]

__device__ __forceinline__ ushort f2b(float f) {          // RNE fp32->bf16
    uint u = __float_as_uint(f);
    u += 0x7FFFu + ((u >> 16) & 1u);
    return (ushort)(u >> 16);
}
__device__ __forceinline__ short8 pk8(float4 a, float4 b) {
    short8 r;
    r[0]=(short)f2b(a.x); r[1]=(short)f2b(a.y); r[2]=(short)f2b(a.z); r[3]=(short)f2b(a.w);
    r[4]=(short)f2b(b.x); r[5]=(short)f2b(b.y); r[6]=(short)f2b(b.z); r[7]=(short)f2b(b.w);
    return r;
}

// ---------------- K1: q -> qkp, vnode. MFMA with RAW weights ---------------
// grid 256 = (rt 32 x ct 4 x m 2), 256 thr (4 waves). Block: 16 rows x 64 c.
__global__ __launch_bounds__(256, 4)
void k1_proj(const float* __restrict__ x, const float* __restrict__ Wq,
             const float* __restrict__ Wv, const float* __restrict__ Wk,
             const float* __restrict__ bq, const float* __restrict__ bv,
             float* __restrict__ vnode, ushort* __restrict__ qkp) {
    __shared__ float xL[16][264];   // stride 264 (16B-aligned rows)
    __shared__ float qls[16][66];   // q slice [row][c-local 64]
    int tid = threadIdx.x;
    int w = tid >> 6, lane = tid & 63, g = lane >> 4, r = lane & 15;
    int m  = blockIdx.x & 1;
    int ct = (blockIdx.x >> 1) & 3;
    int rt = blockIdx.x >> 3;
    int r0 = rt*16, c0 = ct*64;

    #pragma unroll
    for (int it = 0; it < 4; ++it) {     // stage x[16][256]
        int fid = (tid + 256*it)*4;
        int rr = fid >> 8, k = fid & 255;
        *(float4*)&xL[rr][k] = *(const float4*)&x[(size_t)(r0+rr)*256 + k];
    }
    __syncthreads();

    int c = c0 + w*16 + r;               // B-frag col (lane&15 = n)
    const float* Wrow = m ? (Wv + (size_t)c*320) : (Wq + (size_t)c*256);
    floatx4 acc = {0.f,0.f,0.f,0.f};
    #pragma unroll
    for (int kt = 0; kt < 8; ++kt) {
        int k0 = kt*32 + g*8;
        short8 af = pk8(*(float4*)&xL[r][k0], *(float4*)&xL[r][k0+4]);
        short8 bf = pk8(*(const float4*)&Wrow[k0], *(const float4*)&Wrow[k0+4]);
        acc = __builtin_amdgcn_mfma_f32_16x16x32_bf16(af, bf, acc, 0,0,0);
    }
    float bb = m ? bv[c] : bq[c];
    if (m) {   // vnode out (D: row=4g+i, col=r)
        #pragma unroll
        for (int i = 0; i < 4; ++i)
            vnode[(size_t)(r0 + 4*g + i)*256 + c] = acc[i] + bb;
    } else {   // q slice -> LDS, then qkp (raw Wk edge cols, coalesced)
        #pragma unroll
        for (int i = 0; i < 4; ++i)
            qls[4*g + i][w*16 + r] = acc[i] + bb;
        __syncthreads();
        int rr = tid >> 4, es = tid & 15;        // row, e-quad
        int h0 = ct*2;
        float a0[4] = {0,0,0,0}, a1[4] = {0,0,0,0};
        const float* wk0 = Wk + (size_t)(h0*32)*320 + 256 + es*4;
        const float* wk1 = Wk + (size_t)((h0+1)*32)*320 + 256 + es*4;
        #pragma unroll 8
        for (int d = 0; d < 32; ++d) {
            float q0 = qls[rr][d];
            float q1 = qls[rr][32 + d];
            float4 w0 = *(const float4*)&wk0[(size_t)d*320];
            float4 w1 = *(const float4*)&wk1[(size_t)d*320];
            a0[0]+=q0*w0.x; a0[1]+=q0*w0.y; a0[2]+=q0*w0.z; a0[3]+=q0*w0.w;
            a1[0]+=q1*w1.x; a1[1]+=q1*w1.y; a1[2]+=q1*w1.z; a1[3]+=q1*w1.w;
        }
        const float s = 0.17677669529663687f;    // 1/sqrt(32)
        ushort4 u0, u1;
        u0.x=f2b(a0[0]*s); u0.y=f2b(a0[1]*s); u0.z=f2b(a0[2]*s); u0.w=f2b(a0[3]*s);
        u1.x=f2b(a1[0]*s); u1.y=f2b(a1[1]*s); u1.z=f2b(a1[2]*s); u1.w=f2b(a1[3]*s);
        size_t base = (size_t)(r0 + rr)*512;
        *(ushort4*)&qkp[base + h0*64 + es*4]     = u0;
        *(ushort4*)&qkp[base + (h0+1)*64 + es*4] = u1;
    }
}

// ---------------- K2: per-row attention (MFMA logits + MFMA agg) -----------
// grid 512, 256 thr (4 waves), ~30KB LDS.
__global__ __launch_bounds__(256, 4)
void k2_attn(const float* __restrict__ edge, const int* __restrict__ msk,
             const ushort* __restrict__ qkp, ushort* __restrict__ aggO) {
    __shared__ ushort edsA[128][72];   // edge bf16 row-major, 16B-aligned rows
    __shared__ ushort qkpL[16][64];    // rows 8..15 zero
    __shared__ float  attL[8][132];    // masked logits
    __shared__ ushort attT[16][136];   // att bf16 [h][j], rows 8..15 zero
    __shared__ float  mval[128];
    int tid = threadIdx.x;
    int w = tid >> 6, lane = tid & 63, g = lane >> 4, r = lane & 15;
    int row = blockIdx.x;

    float4 ef[8];
    const float* eg = edge + (size_t)row*8192;
    #pragma unroll
    for (int it = 0; it < 8; ++it)
        ef[it] = *(const float4*)(eg + (size_t)(tid + 256*it)*4);

    {   // qkp stage (+ zero pad rows 8..15)
        ushort* qf = (ushort*)qkpL;
        *(uint*)&qf[tid*2]       = *(const uint*)&qkp[(size_t)row*512 + tid*2];
        *(uint*)&qf[512 + tid*2] = 0u;
    }
    if (tid < 128) mval[tid] = (msk[(size_t)row*128 + tid] != 0) ? 1.0f : 0.0f;
    if (tid < 136) {
        #pragma unroll
        for (int hp = 8; hp < 16; ++hp) attT[hp][tid] = 0;
    }
    #pragma unroll
    for (int it = 0; it < 8; ++it) {   // edge -> bf16 LDS
        int fid = (tid + 256*it)*4;
        int j = fid >> 6, e = fid & 63;
        uint lo = (uint)f2b(ef[it].x) | ((uint)f2b(ef[it].y) << 16);
        uint hi = (uint)f2b(ef[it].z) | ((uint)f2b(ef[it].w) << 16);
        *(uint2*)&edsA[j][e] = make_uint2(lo, hi);
    }
    __syncthreads();

    {   // logits MFMA: D[j-local][h]; wave w -> mt = 2w, 2w+1
        #pragma unroll
        for (int mi = 0; mi < 2; ++mi) {
            int mt = w*2 + mi;
            floatx4 acc = {0,0,0,0};
            #pragma unroll
            for (int kt = 0; kt < 2; ++kt) {
                short8 af = *(short8*)&edsA[mt*16 + r][kt*32 + g*8];
                short8 bf = *(short8*)&qkpL[r][kt*32 + g*8];
                acc = __builtin_amdgcn_mfma_f32_16x16x32_bf16(af, bf, acc, 0,0,0);
            }
            if (r < 8) {
                #pragma unroll
                for (int i = 0; i < 4; ++i) {
                    int j = mt*16 + 4*g + i;
                    attL[r][j] = (mval[j] > 0.5f) ? acc[i] : SENT;
                }
            }
        }
    }
    __syncthreads();

    {   // softmax: wave w -> heads 2w, 2w+1 (proven r7 pattern)
        #pragma unroll
        for (int hh = 0; hh < 2; ++hh) {
            int h = w*2 + hh;
            float v0 = attL[h][lane];
            float v1 = attL[h][64 + lane];
            float mx = fmaxf(v0, v1);
            #pragma unroll
            for (int off = 32; off >= 1; off >>= 1) mx = fmaxf(mx, __shfl_xor(mx, off));
            float e0 = __expf(v0 - mx), e1 = __expf(v1 - mx);
            float sm = e0 + e1;
            #pragma unroll
            for (int off = 32; off >= 1; off >>= 1) sm += __shfl_xor(sm, off);
            float inv = 1.0f / sm;
            attT[h][lane]      = f2b(e0 * inv);
            attT[h][64 + lane] = f2b(e1 * inv);
        }
    }
    __syncthreads();

    {   // agg MFMA: D[h][e]; wave w = e-tile. B-frag gathered u16 from edsA.
        floatx4 acc = {0,0,0,0};
        #pragma unroll
        for (int kt = 0; kt < 4; ++kt) {
            short8 a2 = *(short8*)&attT[r][kt*32 + g*8];
            short8 b2;
            #pragma unroll
            for (int jj = 0; jj < 8; ++jj)
                b2[jj] = (short)edsA[kt*32 + g*8 + jj][w*16 + r];
            acc = __builtin_amdgcn_mfma_f32_16x16x32_bf16(a2, b2, acc, 0,0,0);
        }
        #pragma unroll
        for (int i = 0; i < 4; ++i) {
            int h = 4*g + i;
            if (h < 8)
                aggO[(size_t)row*512 + h*64 + w*16 + r] = f2b(acc[i]);
        }
    }
}

// ---------------- K3: y = vnode + agg@WvE^T; out = y@Wp^T + bp (MFMA) ------
// grid 128 = (rt 32 x ob 4), 256 thr. Raw Wv-edge / Wp rows as B-frags.
__global__ __launch_bounds__(256, 2)
void k3_out(const float* __restrict__ vnode, const ushort* __restrict__ aggI,
            const float* __restrict__ Wv, const float* __restrict__ Wp,
            const float* __restrict__ bp, float* __restrict__ out) {
    __shared__ ushort yL[16][264];
    int tid = threadIdx.x;
    int w = tid >> 6, lane = tid & 63, g = lane >> 4, r = lane & 15;
    int rt = blockIdx.x >> 2, ob = blockIdx.x & 3;
    int r0 = rt*16, o0 = ob*64;

    {   // y phase: wave w -> 4 (head, c-subtile) pairs
        #pragma unroll
        for (int pi = 0; pi < 4; ++pi) {
            int p = w*4 + pi, h = p >> 1, ntl = p & 1;
            int c = h*32 + ntl*16 + r;
            floatx4 acc;
            #pragma unroll
            for (int i = 0; i < 4; ++i)
                acc[i] = vnode[(size_t)(r0 + 4*g + i)*256 + c];
            #pragma unroll
            for (int kt = 0; kt < 2; ++kt) {
                short8 af = *(const short8*)&aggI[(size_t)(r0 + r)*512 + h*64 + kt*32 + g*8];
                const float* wr = Wv + (size_t)c*320 + 256 + kt*32 + g*8;
                short8 bf = pk8(*(const float4*)wr, *(const float4*)(wr + 4));
                acc = __builtin_amdgcn_mfma_f32_16x16x32_bf16(af, bf, acc, 0,0,0);
            }
            #pragma unroll
            for (int i = 0; i < 4; ++i)
                yL[4*g + i][c] = f2b(acc[i]);
        }
    }
    __syncthreads();

    {   // out phase: wave w = o-subtile
        int o = o0 + w*16 + r;
        floatx4 acc = {0,0,0,0};
        const float* wr = Wp + (size_t)o*256;
        #pragma unroll
        for (int kt = 0; kt < 8; ++kt) {
            int k0 = kt*32 + g*8;
            short8 af = *(short8*)&yL[r][k0];
            short8 bf = pk8(*(const float4*)&wr[k0], *(const float4*)&wr[k0+4]);
            acc = __builtin_amdgcn_mfma_f32_16x16x32_bf16(af, bf, acc, 0,0,0);
        }
        float bb = bp[o];
        #pragma unroll
        for (int i = 0; i < 4; ++i)
            out[(size_t)(r0 + 4*g + i)*256 + o] = acc[i] + bb;
    }
}

extern "C" void kernel_launch(void* const* d_in, const int* in_sizes, int n_in,
                              void* d_out, int out_size, void* d_ws, size_t ws_size,
                              hipStream_t stream) {
    (void)in_sizes; (void)n_in; (void)out_size; (void)ws_size;
    const float* x    = (const float*)d_in[0];
    // d_in[1] aux_x: unused by reference
    const int*   msk  = (const int*)d_in[2];
    const float* edge = (const float*)d_in[3];
    const float* Wq   = (const float*)d_in[4];
    const float* bq   = (const float*)d_in[5];
    const float* Wk   = (const float*)d_in[6];
    // d_in[7] bk: constant over j -> cancels in softmax
    const float* Wv   = (const float*)d_in[8];
    const float* bv   = (const float*)d_in[9];
    const float* Wp   = (const float*)d_in[10];
    const float* bp   = (const float*)d_in[11];
    float* out = (float*)d_out;
    float* ws  = (float*)d_ws;

    ushort* qkp   = (ushort*)(ws + OFF_QKP);
    ushort* agg   = (ushort*)(ws + OFF_AGG);
    float*  vnode = ws + OFF_VNODE;

    k1_proj<<<256, 256, 0, stream>>>(x, Wq, Wv, Wk, bq, bv, vnode, qkp);
    k2_attn<<<512, 256, 0, stream>>>(edge, msk, qkp, agg);
    k3_out<<<128, 256, 0, stream>>>(vnode, agg, Wv, Wp, bp, out);
}